// Round 5
// baseline (1782.653 us; speedup 1.0000x reference)
//
#include <hip/hip_runtime.h>
#include <hip/hip_bf16.h>

#define H 128
#define F3H 384
#define E_RBF 20
#define NLAYER 3

__device__ __forceinline__ float silu_f(float x) { return x / (1.0f + __expf(-x)); }

constexpr float PI_F = 3.14159265358979323846f;
constexpr float CUT = 5.0f;

// ---------------- K1: per-edge geometry: rbf, fcut, unit ----------------
__global__ __launch_bounds__(256) void edge_geom(
    const float* __restrict__ ediff, const float* __restrict__ edist,
    float* __restrict__ rbf, float* __restrict__ fcut, float* __restrict__ unit, int nE) {
  int e = blockIdx.x * blockDim.x + threadIdx.x;
  if (e >= nE) return;
  float d = edist[e];
  float inv = 1.0f / d;
  #pragma unroll
  for (int n = 0; n < E_RBF; n++) {
    rbf[(size_t)e * E_RBF + n] = sinf(d * (float)(n + 1) * (PI_F / CUT)) * inv;
  }
  fcut[e] = (d < CUT) ? 0.5f * (cosf(PI_F * d / CUT) + 1.0f) : 0.0f;
  #pragma unroll
  for (int k = 0; k < 3; k++) unit[(size_t)e * 3 + k] = ediff[(size_t)e * 3 + k] * inv;
}

// ---------------- K2: node init: ns = embed[z], nv = 0 ----------------
__global__ __launch_bounds__(H) void node_init(
    const int* __restrict__ z, const float* __restrict__ embed,
    float* __restrict__ ns, float* __restrict__ nv, int N) {
  int i = blockIdx.x;
  int h = threadIdx.x;
  ns[(size_t)i * H + h] = embed[(size_t)z[i] * H + h];
  #pragma unroll
  for (int d = 0; d < 3; d++) nv[(size_t)i * F3H + d * H + h] = 0.0f;
}

// ---------------- K3: scalar message MLP: so = silu(ns@W1+b1)@W2+b2 ----------------
__global__ __launch_bounds__(H) void scalar_mlp(
    const float* __restrict__ ns,
    const float* __restrict__ W1, const float* __restrict__ b1,
    const float* __restrict__ W2, const float* __restrict__ b2,
    float* __restrict__ so, int N) {
  __shared__ float s_x[H];
  __shared__ float s_h1[H];
  int i = blockIdx.x;
  int h = threadIdx.x;
  s_x[h] = ns[(size_t)i * H + h];
  __syncthreads();
  float acc = b1[h];
  for (int k = 0; k < H; k++) acc += s_x[k] * W1[k * H + h];
  s_h1[h] = silu_f(acc);
  __syncthreads();
  #pragma unroll
  for (int j = 0; j < 3; j++) {
    int c = j * H + h;
    float a = b2[c];
    for (int k = 0; k < H; k++) a += s_h1[k] * W2[k * F3H + c];
    so[(size_t)i * F3H + c] = a;
  }
}

// ---------------- K4: copy nv -> nvm (double buffer for scatter) ----------------
__global__ __launch_bounds__(256) void copyf(const float* __restrict__ a, float* __restrict__ b, int n) {
  int i = blockIdx.x * blockDim.x + threadIdx.x;
  if (i < n) b[i] = a[i];
}

// ---------------- K5: per-edge message + scatter (atomics) ----------------
__global__ __launch_bounds__(H) void message(
    const int* __restrict__ edge, const float* __restrict__ rbf,
    const float* __restrict__ fcut, const float* __restrict__ unit,
    const float* __restrict__ Wf, const float* __restrict__ bfb,
    const float* __restrict__ so, const float* __restrict__ nv,
    float* __restrict__ ns_out, float* __restrict__ nv_out, int nE) {
  __shared__ float s_W[E_RBF * F3H];   // 30 KB
  __shared__ float s_b[F3H];
  int h = threadIdx.x;
  for (int t = h; t < E_RBF * F3H; t += H) s_W[t] = Wf[t];
  for (int t = h; t < F3H; t += H) s_b[t] = bfb[t];
  __syncthreads();

  for (int e = blockIdx.x; e < nE; e += gridDim.x) {
    int dst = edge[2 * e];
    int src = edge[2 * e + 1];
    float fc = fcut[e];
    float u0 = unit[3 * (size_t)e], u1 = unit[3 * (size_t)e + 1], u2 = unit[3 * (size_t)e + 2];
    float r[E_RBF];
    #pragma unroll
    for (int k = 0; k < E_RBF; k++) r[k] = rbf[(size_t)e * E_RBF + k];

    float f0 = s_b[h], f1 = s_b[H + h], f2 = s_b[2 * H + h];
    #pragma unroll
    for (int k = 0; k < E_RBF; k++) {
      float rk = r[k];
      f0 += rk * s_W[k * F3H + h];
      f1 += rk * s_W[k * F3H + H + h];
      f2 += rk * s_W[k * F3H + 2 * H + h];
    }
    f0 *= fc; f1 *= fc; f2 *= fc;

    const float* sop = so + (size_t)src * F3H;
    float gsv = f0 * sop[h];
    float gev = f1 * sop[H + h];
    float msg_s = f2 * sop[2 * H + h];

    atomicAdd(&ns_out[(size_t)dst * H + h], msg_s);

    const float* nvp = nv + (size_t)src * F3H;
    atomicAdd(&nv_out[(size_t)dst * F3H + h],         nvp[h] * gsv + gev * u0);
    atomicAdd(&nv_out[(size_t)dst * F3H + H + h],     nvp[H + h] * gsv + gev * u1);
    atomicAdd(&nv_out[(size_t)dst * F3H + 2 * H + h], nvp[2 * H + h] * gsv + gev * u2);
  }
}

// ---------------- K6: per-node update ----------------
__global__ __launch_bounds__(H) void update(
    float* __restrict__ ns, const float* __restrict__ nv_in, float* __restrict__ nv_out,
    const float* __restrict__ Uw, const float* __restrict__ Ub,
    const float* __restrict__ Vw, const float* __restrict__ Vb,
    const float* __restrict__ W1, const float* __restrict__ b1,
    const float* __restrict__ W2, const float* __restrict__ b2, int N) {
  __shared__ float s_nv[3][H];
  __shared__ float s_in[2 * H];
  __shared__ float s_h1[H];
  int i = blockIdx.x;
  int h = threadIdx.x;
  #pragma unroll
  for (int d = 0; d < 3; d++) s_nv[d][h] = nv_in[(size_t)i * F3H + d * H + h];
  float nsv = ns[(size_t)i * H + h];
  s_in[H + h] = nsv;
  __syncthreads();

  float ub = Ub[h], vb = Vb[h];
  float aU0 = ub, aU1 = ub, aU2 = ub;
  float aV0 = vb, aV1 = vb, aV2 = vb;
  for (int k = 0; k < H; k++) {
    float wu = Uw[k * H + h];
    float wv = Vw[k * H + h];
    float x0 = s_nv[0][k], x1 = s_nv[1][k], x2 = s_nv[2][k];
    aU0 += x0 * wu; aU1 += x1 * wu; aU2 += x2 * wu;
    aV0 += x0 * wv; aV1 += x1 * wv; aV2 += x2 * wv;
  }
  float vnorm = sqrtf(aV0 * aV0 + aV1 * aV1 + aV2 * aV2);
  s_in[h] = vnorm;
  __syncthreads();

  float acc = b1[h];
  for (int k = 0; k < 2 * H; k++) acc += s_in[k] * W1[k * H + h];
  s_h1[h] = silu_f(acc);
  __syncthreads();

  float avv = b2[h], asv = b2[H + h], ass = b2[2 * H + h];
  for (int k = 0; k < H; k++) {
    float hk = s_h1[k];
    avv += hk * W2[k * F3H + h];
    asv += hk * W2[k * F3H + H + h];
    ass += hk * W2[k * F3H + 2 * H + h];
  }
  float dotUV = aU0 * aV0 + aU1 * aV1 + aU2 * aV2;

  ns[(size_t)i * H + h] = nsv + asv * dotUV + ass;
  nv_out[(size_t)i * F3H + h]         = s_nv[0][h] + avv * aU0;
  nv_out[(size_t)i * F3H + H + h]     = s_nv[1][h] + avv * aU1;
  nv_out[(size_t)i * F3H + 2 * H + h] = s_nv[2][h] + avv * aU2;
}

// ---------------- K7: readout -> FP32 out (the round-4 fix) ----------------
__global__ __launch_bounds__(H) void readout(
    const float* __restrict__ ns,
    const float* __restrict__ W1, const float* __restrict__ b1,
    const float* __restrict__ W2, const float* __restrict__ b2,
    float* __restrict__ out, int N) {
  __shared__ float s_x[H];
  __shared__ float s_h1[H];
  int i = blockIdx.x;
  int h = threadIdx.x;
  s_x[h] = ns[(size_t)i * H + h];
  __syncthreads();
  float acc = b1[h];
  for (int k = 0; k < H; k++) acc += s_x[k] * W1[k * H + h];
  s_h1[h] = silu_f(acc);
  __syncthreads();
  float o = b2[h];
  for (int k = 0; k < H; k++) o += s_h1[k] * W2[k * H + h];
  out[(size_t)i * H + h] = o;   // fp32 output, per reference dtype
}

extern "C" void kernel_launch(void* const* d_in, const int* in_sizes, int n_in,
                              void* d_out, int out_size, void* d_ws, size_t ws_size,
                              hipStream_t stream) {
  const int*   z     = (const int*)d_in[0];
  const int*   edge  = (const int*)d_in[1];
  const float* ediff = (const float*)d_in[2];
  const float* edist = (const float*)d_in[3];
  const float* embed = (const float*)d_in[4];
  const float* mfw   = (const float*)d_in[5];
  const float* mfb   = (const float*)d_in[6];
  const float* mw1   = (const float*)d_in[7];
  const float* mb1   = (const float*)d_in[8];
  const float* mw2   = (const float*)d_in[9];
  const float* mb2   = (const float*)d_in[10];
  const float* uUw   = (const float*)d_in[11];
  const float* uUb   = (const float*)d_in[12];
  const float* uVw   = (const float*)d_in[13];
  const float* uVb   = (const float*)d_in[14];
  const float* uw1   = (const float*)d_in[15];
  const float* ub1   = (const float*)d_in[16];
  const float* uw2   = (const float*)d_in[17];
  const float* ub2   = (const float*)d_in[18];
  const float* rw1   = (const float*)d_in[19];
  const float* rb1   = (const float*)d_in[20];
  const float* rw2   = (const float*)d_in[21];
  const float* rb2   = (const float*)d_in[22];

  const int N  = in_sizes[0];   // 10000
  const int nE = in_sizes[3];   // 160000

  float* ws = (float*)d_ws;
  size_t off = 0;
  float* rbf  = ws + off; off += (size_t)nE * E_RBF;
  float* fcut = ws + off; off += (size_t)nE;
  float* unit = ws + off; off += (size_t)nE * 3;
  float* ns   = ws + off; off += (size_t)N * H;
  float* nv   = ws + off; off += (size_t)N * F3H;
  float* nvm  = ws + off; off += (size_t)N * F3H;
  float* so   = ws + off; off += (size_t)N * F3H;

  edge_geom<<<(nE + 255) / 256, 256, 0, stream>>>(ediff, edist, rbf, fcut, unit, nE);
  node_init<<<N, H, 0, stream>>>(z, embed, ns, nv, N);

  for (int l = 0; l < NLAYER; l++) {
    scalar_mlp<<<N, H, 0, stream>>>(ns, mw1 + (size_t)l * H * H, mb1 + (size_t)l * H,
                                    mw2 + (size_t)l * H * F3H, mb2 + (size_t)l * F3H, so, N);
    copyf<<<(N * F3H + 255) / 256, 256, 0, stream>>>(nv, nvm, N * F3H);
    message<<<4096, H, 0, stream>>>(edge, rbf, fcut, unit,
                                    mfw + (size_t)l * E_RBF * F3H, mfb + (size_t)l * F3H,
                                    so, nv, ns, nvm, nE);
    update<<<N, H, 0, stream>>>(ns, nvm, nv,
                                uUw + (size_t)l * H * H, uUb + (size_t)l * H,
                                uVw + (size_t)l * H * H, uVb + (size_t)l * H,
                                uw1 + (size_t)l * 2 * H * H, ub1 + (size_t)l * H,
                                uw2 + (size_t)l * H * F3H, ub2 + (size_t)l * F3H, N);
  }

  readout<<<N, H, 0, stream>>>(ns, rw1, rb1, rw2, rb2, (float*)d_out, N);
}

// Round 6
// 1224.599 us; speedup vs baseline: 1.4557x; 1.4557x over previous
//
#include <hip/hip_runtime.h>
#include <hip/hip_bf16.h>

#define H 128
#define F3H 384
#define E_RBF 20
#define NLAYER 3

__device__ __forceinline__ float silu_f(float x) { return x / (1.0f + __expf(-x)); }

constexpr float PI_F = 3.14159265358979323846f;
constexpr float CUT = 5.0f;

// ---------------- CSR build: histogram / scan / fill ----------------
__global__ __launch_bounds__(256) void csr_hist(
    const int* __restrict__ edge, int* __restrict__ cnt, int nE) {
  int e = blockIdx.x * blockDim.x + threadIdx.x;
  if (e < nE) atomicAdd(&cnt[edge[2 * e]], 1);
}

__global__ __launch_bounds__(256) void csr_scan(
    const int* __restrict__ cnt, int* __restrict__ rowstart, int* __restrict__ cur, int N) {
  __shared__ int part[256];
  int t = threadIdx.x;
  int chunk = (N + 255) / 256;
  int lo = t * chunk; if (lo > N) lo = N;
  int hi = lo + chunk; if (hi > N) hi = N;
  int s = 0;
  for (int i = lo; i < hi; i++) s += cnt[i];
  part[t] = s;
  __syncthreads();
  if (t == 0) {
    int r = 0;
    for (int i = 0; i < 256; i++) { int v = part[i]; part[i] = r; r += v; }
  }
  __syncthreads();
  int r = part[t];
  for (int i = lo; i < hi; i++) { rowstart[i] = r; cur[i] = r; r += cnt[i]; }
}

__global__ __launch_bounds__(256) void csr_fill(
    const int* __restrict__ edge, int* __restrict__ cur, int* __restrict__ elist, int nE) {
  int e = blockIdx.x * blockDim.x + threadIdx.x;
  if (e < nE) {
    int d = edge[2 * e];
    int p = atomicAdd(&cur[d], 1);
    elist[p] = e;
  }
}

// ---------------- node init: ns = embed[z], nv = 0 ----------------
__global__ __launch_bounds__(H) void node_init(
    const int* __restrict__ z, const float* __restrict__ embed,
    float* __restrict__ ns, float* __restrict__ nv, int N) {
  int i = blockIdx.x;
  int h = threadIdx.x;
  ns[(size_t)i * H + h] = embed[(size_t)z[i] * H + h];
  #pragma unroll
  for (int d = 0; d < 3; d++) nv[(size_t)i * F3H + d * H + h] = 0.0f;
}

// ---------------- scalar message MLP: so = silu(ns@W1+b1)@W2+b2 ----------------
__global__ __launch_bounds__(H) void scalar_mlp(
    const float* __restrict__ ns,
    const float* __restrict__ W1, const float* __restrict__ b1,
    const float* __restrict__ W2, const float* __restrict__ b2,
    float* __restrict__ so, int N) {
  __shared__ float s_x[H];
  __shared__ float s_h1[H];
  int i = blockIdx.x;
  int h = threadIdx.x;
  s_x[h] = ns[(size_t)i * H + h];
  __syncthreads();
  float acc = b1[h];
  for (int k = 0; k < H; k++) acc += s_x[k] * W1[k * H + h];
  s_h1[h] = silu_f(acc);
  __syncthreads();
  #pragma unroll
  for (int j = 0; j < 3; j++) {
    int c = j * H + h;
    float a = b2[c];
    for (int k = 0; k < H; k++) a += s_h1[k] * W2[k * F3H + c];
    so[(size_t)i * F3H + c] = a;
  }
}

// ---------------- message (gather form): block = dst node, NO atomics ----------------
// Filter weights live in registers: lane h needs Wf[k*384 + {h,128+h,256+h}], k<20.
// rbf via Chebyshev recurrence sin(k*th); fcut/unit inline from edist/ediff.
__global__ __launch_bounds__(H) void message2(
    const int* __restrict__ edge, const int* __restrict__ rowstart,
    const int* __restrict__ cnt, const int* __restrict__ elist,
    const float* __restrict__ edist, const float* __restrict__ ediff,
    const float* __restrict__ Wf, const float* __restrict__ bfb,
    const float* __restrict__ so, const float* __restrict__ nvA,
    float* __restrict__ ns, float* __restrict__ nvB, int N) {
  int i = blockIdx.x;
  int h = threadIdx.x;

  float wf0[E_RBF], wf1[E_RBF], wf2[E_RBF];
  #pragma unroll
  for (int k = 0; k < E_RBF; k++) {
    wf0[k] = Wf[k * F3H + h];
    wf1[k] = Wf[k * F3H + H + h];
    wf2[k] = Wf[k * F3H + 2 * H + h];
  }
  float bb0 = bfb[h], bb1 = bfb[H + h], bb2 = bfb[2 * H + h];

  float accs = 0.0f, a0 = 0.0f, a1 = 0.0f, a2 = 0.0f;
  int jlo = rowstart[i], jhi = jlo + cnt[i];
  for (int j = jlo; j < jhi; j++) {
    int e = elist[j];
    int src = edge[2 * e + 1];
    float d = edist[e];
    float inv = 1.0f / d;
    float th = d * (PI_F / CUT);
    float s1 = __sinf(th) , c1 = __cosf(th);
    // use precise sinf/cosf to stay near reference
    s1 = sinf(th); c1 = cosf(th);
    float fc = (d < CUT) ? 0.5f * (c1 + 1.0f) : 0.0f;
    float u0 = ediff[3 * (size_t)e] * inv;
    float u1 = ediff[3 * (size_t)e + 1] * inv;
    float u2 = ediff[3 * (size_t)e + 2] * inv;

    float f0 = bb0, f1 = bb1, f2 = bb2;
    float twoc = 2.0f * c1;
    float skp = 0.0f, sk = s1;           // sin(k*th), k=1
    #pragma unroll
    for (int k = 0; k < E_RBF; k++) {
      float rk = sk * inv;
      f0 += rk * wf0[k];
      f1 += rk * wf1[k];
      f2 += rk * wf2[k];
      float nx = twoc * sk - skp;
      skp = sk; sk = nx;
    }
    f0 *= fc; f1 *= fc; f2 *= fc;

    const float* sop = so + (size_t)src * F3H;
    float gsv = f0 * sop[h];
    float gev = f1 * sop[H + h];
    accs += f2 * sop[2 * H + h];

    const float* nvp = nvA + (size_t)src * F3H;
    a0 += nvp[h]         * gsv + gev * u0;
    a1 += nvp[H + h]     * gsv + gev * u1;
    a2 += nvp[2 * H + h] * gsv + gev * u2;
  }

  ns[(size_t)i * H + h] += accs;
  const float* nvi = nvA + (size_t)i * F3H;
  nvB[(size_t)i * F3H + h]         = nvi[h] + a0;
  nvB[(size_t)i * F3H + H + h]     = nvi[H + h] + a1;
  nvB[(size_t)i * F3H + 2 * H + h] = nvi[2 * H + h] + a2;
}

// ---------------- per-node update (in-place on ns and nv) ----------------
__global__ __launch_bounds__(H) void update(
    float* __restrict__ ns, float* __restrict__ nv,
    const float* __restrict__ Uw, const float* __restrict__ Ub,
    const float* __restrict__ Vw, const float* __restrict__ Vb,
    const float* __restrict__ W1, const float* __restrict__ b1,
    const float* __restrict__ W2, const float* __restrict__ b2, int N) {
  __shared__ float s_nv[3][H];
  __shared__ float s_in[2 * H];
  __shared__ float s_h1[H];
  int i = blockIdx.x;
  int h = threadIdx.x;
  #pragma unroll
  for (int d = 0; d < 3; d++) s_nv[d][h] = nv[(size_t)i * F3H + d * H + h];
  float nsv = ns[(size_t)i * H + h];
  s_in[H + h] = nsv;
  __syncthreads();

  float ub = Ub[h], vb = Vb[h];
  float aU0 = ub, aU1 = ub, aU2 = ub;
  float aV0 = vb, aV1 = vb, aV2 = vb;
  for (int k = 0; k < H; k++) {
    float wu = Uw[k * H + h];
    float wv = Vw[k * H + h];
    float x0 = s_nv[0][k], x1 = s_nv[1][k], x2 = s_nv[2][k];
    aU0 += x0 * wu; aU1 += x1 * wu; aU2 += x2 * wu;
    aV0 += x0 * wv; aV1 += x1 * wv; aV2 += x2 * wv;
  }
  float vnorm = sqrtf(aV0 * aV0 + aV1 * aV1 + aV2 * aV2);
  s_in[h] = vnorm;
  __syncthreads();

  float acc = b1[h];
  for (int k = 0; k < 2 * H; k++) acc += s_in[k] * W1[k * H + h];
  s_h1[h] = silu_f(acc);
  __syncthreads();

  float avv = b2[h], asv = b2[H + h], ass = b2[2 * H + h];
  for (int k = 0; k < H; k++) {
    float hk = s_h1[k];
    avv += hk * W2[k * F3H + h];
    asv += hk * W2[k * F3H + H + h];
    ass += hk * W2[k * F3H + 2 * H + h];
  }
  float dotUV = aU0 * aV0 + aU1 * aV1 + aU2 * aV2;

  ns[(size_t)i * H + h] = nsv + asv * dotUV + ass;
  nv[(size_t)i * F3H + h]         = s_nv[0][h] + avv * aU0;
  nv[(size_t)i * F3H + H + h]     = s_nv[1][h] + avv * aU1;
  nv[(size_t)i * F3H + 2 * H + h] = s_nv[2][h] + avv * aU2;
}

// ---------------- readout -> fp32 out ----------------
__global__ __launch_bounds__(H) void readout(
    const float* __restrict__ ns,
    const float* __restrict__ W1, const float* __restrict__ b1,
    const float* __restrict__ W2, const float* __restrict__ b2,
    float* __restrict__ out, int N) {
  __shared__ float s_x[H];
  __shared__ float s_h1[H];
  int i = blockIdx.x;
  int h = threadIdx.x;
  s_x[h] = ns[(size_t)i * H + h];
  __syncthreads();
  float acc = b1[h];
  for (int k = 0; k < H; k++) acc += s_x[k] * W1[k * H + h];
  s_h1[h] = silu_f(acc);
  __syncthreads();
  float o = b2[h];
  for (int k = 0; k < H; k++) o += s_h1[k] * W2[k * H + h];
  out[(size_t)i * H + h] = o;
}

extern "C" void kernel_launch(void* const* d_in, const int* in_sizes, int n_in,
                              void* d_out, int out_size, void* d_ws, size_t ws_size,
                              hipStream_t stream) {
  const int*   z     = (const int*)d_in[0];
  const int*   edge  = (const int*)d_in[1];
  const float* ediff = (const float*)d_in[2];
  const float* edist = (const float*)d_in[3];
  const float* embed = (const float*)d_in[4];
  const float* mfw   = (const float*)d_in[5];
  const float* mfb   = (const float*)d_in[6];
  const float* mw1   = (const float*)d_in[7];
  const float* mb1   = (const float*)d_in[8];
  const float* mw2   = (const float*)d_in[9];
  const float* mb2   = (const float*)d_in[10];
  const float* uUw   = (const float*)d_in[11];
  const float* uUb   = (const float*)d_in[12];
  const float* uVw   = (const float*)d_in[13];
  const float* uVb   = (const float*)d_in[14];
  const float* uw1   = (const float*)d_in[15];
  const float* ub1   = (const float*)d_in[16];
  const float* uw2   = (const float*)d_in[17];
  const float* ub2   = (const float*)d_in[18];
  const float* rw1   = (const float*)d_in[19];
  const float* rb1   = (const float*)d_in[20];
  const float* rw2   = (const float*)d_in[21];
  const float* rb2   = (const float*)d_in[22];

  const int N  = in_sizes[0];   // 10000
  const int nE = in_sizes[3];   // 160000

  float* ws = (float*)d_ws;
  size_t off = 0;
  float* ns   = ws + off; off += (size_t)N * H;
  float* nvA  = ws + off; off += (size_t)N * F3H;
  float* nvB  = ws + off; off += (size_t)N * F3H;
  float* so   = ws + off; off += (size_t)N * F3H;
  int* cnt      = (int*)(ws + off); off += N;
  int* rowstart = (int*)(ws + off); off += N;
  int* cur      = (int*)(ws + off); off += N;
  int* elist    = (int*)(ws + off); off += nE;

  // CSR by dst (reused across all 3 layers)
  hipMemsetAsync(cnt, 0, (size_t)N * sizeof(int), stream);
  csr_hist<<<(nE + 255) / 256, 256, 0, stream>>>(edge, cnt, nE);
  csr_scan<<<1, 256, 0, stream>>>(cnt, rowstart, cur, N);
  csr_fill<<<(nE + 255) / 256, 256, 0, stream>>>(edge, cur, elist, nE);

  node_init<<<N, H, 0, stream>>>(z, embed, ns, nvA, N);

  float* nv_cur = nvA;
  float* nv_nxt = nvB;
  for (int l = 0; l < NLAYER; l++) {
    scalar_mlp<<<N, H, 0, stream>>>(ns, mw1 + (size_t)l * H * H, mb1 + (size_t)l * H,
                                    mw2 + (size_t)l * H * F3H, mb2 + (size_t)l * F3H, so, N);
    message2<<<N, H, 0, stream>>>(edge, rowstart, cnt, elist, edist, ediff,
                                  mfw + (size_t)l * E_RBF * F3H, mfb + (size_t)l * F3H,
                                  so, nv_cur, ns, nv_nxt, N);
    update<<<N, H, 0, stream>>>(ns, nv_nxt,
                                uUw + (size_t)l * H * H, uUb + (size_t)l * H,
                                uVw + (size_t)l * H * H, uVb + (size_t)l * H,
                                uw1 + (size_t)l * 2 * H * H, ub1 + (size_t)l * H,
                                uw2 + (size_t)l * H * F3H, ub2 + (size_t)l * F3H, N);
    float* t = nv_cur; nv_cur = nv_nxt; nv_nxt = t;
  }

  readout<<<N, H, 0, stream>>>(ns, rw1, rb1, rw2, rb2, (float*)d_out, N);
}

// Round 7
// 1103.372 us; speedup vs baseline: 1.6156x; 1.1099x over previous
//
#include <hip/hip_runtime.h>
#include <hip/hip_bf16.h>

#define H 128
#define F3H 384
#define E_RBF 20
#define NLAYER 3

__device__ __forceinline__ float silu_f(float x) { return x / (1.0f + __expf(-x)); }

constexpr float PI_F = 3.14159265358979323846f;
constexpr float CUT = 5.0f;

// ---------------- CSR build ----------------
__global__ __launch_bounds__(256) void csr_hist(
    const int* __restrict__ edge, int* __restrict__ cnt, int nE) {
  int e = blockIdx.x * blockDim.x + threadIdx.x;
  if (e < nE) atomicAdd(&cnt[edge[2 * e]], 1);
}

__global__ __launch_bounds__(256) void csr_scan(
    const int* __restrict__ cnt, int* __restrict__ rowstart, int* __restrict__ cur, int N) {
  __shared__ int part[256];
  int t = threadIdx.x;
  int chunk = (N + 255) / 256;
  int lo = t * chunk; if (lo > N) lo = N;
  int hi = lo + chunk; if (hi > N) hi = N;
  int s = 0;
  for (int i = lo; i < hi; i++) s += cnt[i];
  part[t] = s;
  __syncthreads();
  if (t == 0) {
    int r = 0;
    for (int i = 0; i < 256; i++) { int v = part[i]; part[i] = r; r += v; }
  }
  __syncthreads();
  int r = part[t];
  for (int i = lo; i < hi; i++) { rowstart[i] = r; cur[i] = r; r += cnt[i]; }
}

__global__ __launch_bounds__(256) void csr_fill(
    const int* __restrict__ edge, int* __restrict__ cur, int* __restrict__ elist, int nE) {
  int e = blockIdx.x * blockDim.x + threadIdx.x;
  if (e < nE) {
    int d = edge[2 * e];
    int p = atomicAdd(&cur[d], 1);
    elist[p] = e;
  }
}

// ---------------- node init ----------------
__global__ __launch_bounds__(H) void node_init(
    const int* __restrict__ z, const float* __restrict__ embed,
    float* __restrict__ ns, float* __restrict__ nv, int N) {
  int i = blockIdx.x;
  int h = threadIdx.x;
  ns[(size_t)i * H + h] = embed[(size_t)z[i] * H + h];
  #pragma unroll
  for (int d = 0; d < 3; d++) nv[(size_t)i * F3H + d * H + h] = 0.0f;
}

// ---------------- generic register-tiled GEMM ----------------
// C[M,cols] = (A[M,K] @ W[K,cols] + b), optional silu.
// block=256, tile 32 rows x 128 cols, 4x4 per thread, A in LDS (+4 pad).
template<int K, bool ACT>
__global__ __launch_bounds__(256) void gemm_t(
    const float* __restrict__ A, const float* __restrict__ W,
    const float* __restrict__ bias, float* __restrict__ C,
    int M, int cols, int npanels) {
  __shared__ float s_a[32][K + 4];
  int bx = blockIdx.x;
  int panel = bx % npanels;
  int tile  = bx / npanels;
  int i0 = tile * 32;
  int colbase = panel * 128;
  int tid = threadIdx.x;
  for (int idx = tid; idx < 32 * K; idx += 256) {
    int r = idx / K, k = idx - r * K;
    int gr = i0 + r;
    s_a[r][k] = (gr < M) ? A[(size_t)gr * K + k] : 0.0f;
  }
  __syncthreads();
  int mq = tid >> 5, hq = tid & 31;
  int col = colbase + 4 * hq;
  const float* Wp = W + col;
  float acc[4][4] = {};
  for (int k0 = 0; k0 < K; k0 += 4) {
    float4 av[4], wv[4];
    #pragma unroll
    for (int i = 0; i < 4; i++) av[i] = *(const float4*)&s_a[4 * mq + i][k0];
    #pragma unroll
    for (int kk = 0; kk < 4; kk++) wv[kk] = *(const float4*)&Wp[(size_t)(k0 + kk) * cols];
    #pragma unroll
    for (int kk = 0; kk < 4; kk++) {
      #pragma unroll
      for (int i = 0; i < 4; i++) {
        float a = ((const float*)&av[i])[kk];
        acc[i][0] += a * wv[kk].x;
        acc[i][1] += a * wv[kk].y;
        acc[i][2] += a * wv[kk].z;
        acc[i][3] += a * wv[kk].w;
      }
    }
  }
  float4 bj = *(const float4*)&bias[col];
  #pragma unroll
  for (int i = 0; i < 4; i++) {
    int gr = i0 + 4 * mq + i;
    if (gr < M) {
      float4 o;
      o.x = acc[i][0] + bj.x; o.y = acc[i][1] + bj.y;
      o.z = acc[i][2] + bj.z; o.w = acc[i][3] + bj.w;
      if (ACT) { o.x = silu_f(o.x); o.y = silu_f(o.y); o.z = silu_f(o.z); o.w = silu_f(o.w); }
      *(float4*)&C[(size_t)gr * cols + col] = o;
    }
  }
}

// ---------------- dual GEMM: Uv and Vv from same A (cols=128, K=128) ----------------
__global__ __launch_bounds__(256) void gemm_uv(
    const float* __restrict__ A,
    const float* __restrict__ Wu, const float* __restrict__ bu,
    const float* __restrict__ Wv, const float* __restrict__ bv,
    float* __restrict__ Cu, float* __restrict__ Cv, int M) {
  __shared__ float s_a[32][132];
  int i0 = blockIdx.x * 32;
  int tid = threadIdx.x;
  for (int idx = tid; idx < 32 * 128; idx += 256) {
    int r = idx >> 7, k = idx & 127;
    int gr = i0 + r;
    s_a[r][k] = (gr < M) ? A[(size_t)gr * H + k] : 0.0f;
  }
  __syncthreads();
  int mq = tid >> 5, hq = tid & 31;
  int col = 4 * hq;
  const float* Wup = Wu + col;
  const float* Wvp = Wv + col;
  float au[4][4] = {}, av_[4][4] = {};
  for (int k0 = 0; k0 < 128; k0 += 4) {
    float4 aa[4], wu4[4], wv4[4];
    #pragma unroll
    for (int i = 0; i < 4; i++) aa[i] = *(const float4*)&s_a[4 * mq + i][k0];
    #pragma unroll
    for (int kk = 0; kk < 4; kk++) {
      wu4[kk] = *(const float4*)&Wup[(size_t)(k0 + kk) * H];
      wv4[kk] = *(const float4*)&Wvp[(size_t)(k0 + kk) * H];
    }
    #pragma unroll
    for (int kk = 0; kk < 4; kk++) {
      #pragma unroll
      for (int i = 0; i < 4; i++) {
        float a = ((const float*)&aa[i])[kk];
        au[i][0] += a * wu4[kk].x; au[i][1] += a * wu4[kk].y;
        au[i][2] += a * wu4[kk].z; au[i][3] += a * wu4[kk].w;
        av_[i][0] += a * wv4[kk].x; av_[i][1] += a * wv4[kk].y;
        av_[i][2] += a * wv4[kk].z; av_[i][3] += a * wv4[kk].w;
      }
    }
  }
  float4 bu4 = *(const float4*)&bu[col];
  float4 bv4 = *(const float4*)&bv[col];
  #pragma unroll
  for (int i = 0; i < 4; i++) {
    int gr = i0 + 4 * mq + i;
    if (gr < M) {
      float4 ou, ov;
      ou.x = au[i][0] + bu4.x; ou.y = au[i][1] + bu4.y; ou.z = au[i][2] + bu4.z; ou.w = au[i][3] + bu4.w;
      ov.x = av_[i][0] + bv4.x; ov.y = av_[i][1] + bv4.y; ov.z = av_[i][2] + bv4.z; ov.w = av_[i][3] + bv4.w;
      *(float4*)&Cu[(size_t)gr * H + col] = ou;
      *(float4*)&Cv[(size_t)gr * H + col] = ov;
    }
  }
}

// ---------------- update-MLP layer1: A fused from [||Vv||, ns], K=256, silu ----------------
__global__ __launch_bounds__(256) void gemm_mid(
    const float* __restrict__ Vv, const float* __restrict__ ns,
    const float* __restrict__ W, const float* __restrict__ bias,
    float* __restrict__ C, int M) {
  __shared__ float s_a[32][260];
  int i0 = blockIdx.x * 32;
  int tid = threadIdx.x;
  for (int idx = tid; idx < 32 * 256; idx += 256) {
    int r = idx >> 8, k = idx & 255;
    int gr = i0 + r;
    float val = 0.0f;
    if (gr < M) {
      if (k < H) {
        float v0 = Vv[(size_t)(3 * gr + 0) * H + k];
        float v1 = Vv[(size_t)(3 * gr + 1) * H + k];
        float v2 = Vv[(size_t)(3 * gr + 2) * H + k];
        val = sqrtf(v0 * v0 + v1 * v1 + v2 * v2);
      } else {
        val = ns[(size_t)gr * H + (k - H)];
      }
    }
    s_a[r][k] = val;
  }
  __syncthreads();
  int mq = tid >> 5, hq = tid & 31;
  int col = 4 * hq;
  const float* Wp = W + col;
  float acc[4][4] = {};
  for (int k0 = 0; k0 < 256; k0 += 4) {
    float4 aa[4], wv[4];
    #pragma unroll
    for (int i = 0; i < 4; i++) aa[i] = *(const float4*)&s_a[4 * mq + i][k0];
    #pragma unroll
    for (int kk = 0; kk < 4; kk++) wv[kk] = *(const float4*)&Wp[(size_t)(k0 + kk) * H];
    #pragma unroll
    for (int kk = 0; kk < 4; kk++) {
      #pragma unroll
      for (int i = 0; i < 4; i++) {
        float a = ((const float*)&aa[i])[kk];
        acc[i][0] += a * wv[kk].x; acc[i][1] += a * wv[kk].y;
        acc[i][2] += a * wv[kk].z; acc[i][3] += a * wv[kk].w;
      }
    }
  }
  float4 bj = *(const float4*)&bias[col];
  #pragma unroll
  for (int i = 0; i < 4; i++) {
    int gr = i0 + 4 * mq + i;
    if (gr < M) {
      float4 o;
      o.x = silu_f(acc[i][0] + bj.x); o.y = silu_f(acc[i][1] + bj.y);
      o.z = silu_f(acc[i][2] + bj.z); o.w = silu_f(acc[i][3] + bj.w);
      *(float4*)&C[(size_t)gr * H + col] = o;
    }
  }
}

// ---------------- message (gather, no atomics) ----------------
__global__ __launch_bounds__(H) void message2(
    const int* __restrict__ edge, const int* __restrict__ rowstart,
    const int* __restrict__ cnt, const int* __restrict__ elist,
    const float* __restrict__ edist, const float* __restrict__ ediff,
    const float* __restrict__ Wf, const float* __restrict__ bfb,
    const float* __restrict__ so, const float* __restrict__ nvA,
    float* __restrict__ ns, float* __restrict__ nvB, int N) {
  int i = blockIdx.x;
  int h = threadIdx.x;

  float wf0[E_RBF], wf1[E_RBF], wf2[E_RBF];
  #pragma unroll
  for (int k = 0; k < E_RBF; k++) {
    wf0[k] = Wf[k * F3H + h];
    wf1[k] = Wf[k * F3H + H + h];
    wf2[k] = Wf[k * F3H + 2 * H + h];
  }
  float bb0 = bfb[h], bb1 = bfb[H + h], bb2 = bfb[2 * H + h];

  float accs = 0.0f, a0 = 0.0f, a1 = 0.0f, a2 = 0.0f;
  int jlo = rowstart[i], jhi = jlo + cnt[i];
  for (int j = jlo; j < jhi; j++) {
    int e = elist[j];
    int src = edge[2 * e + 1];
    float d = edist[e];
    float inv = 1.0f / d;
    float th = d * (PI_F / CUT);
    float s1 = sinf(th), c1 = cosf(th);
    float fc = (d < CUT) ? 0.5f * (c1 + 1.0f) : 0.0f;
    float u0 = ediff[3 * (size_t)e] * inv;
    float u1 = ediff[3 * (size_t)e + 1] * inv;
    float u2 = ediff[3 * (size_t)e + 2] * inv;

    float f0 = bb0, f1 = bb1, f2 = bb2;
    float twoc = 2.0f * c1;
    float skp = 0.0f, sk = s1;
    #pragma unroll
    for (int k = 0; k < E_RBF; k++) {
      float rk = sk * inv;
      f0 += rk * wf0[k];
      f1 += rk * wf1[k];
      f2 += rk * wf2[k];
      float nx = twoc * sk - skp;
      skp = sk; sk = nx;
    }
    f0 *= fc; f1 *= fc; f2 *= fc;

    const float* sop = so + (size_t)src * F3H;
    float gsv = f0 * sop[h];
    float gev = f1 * sop[H + h];
    accs += f2 * sop[2 * H + h];

    const float* nvp = nvA + (size_t)src * F3H;
    a0 += nvp[h]         * gsv + gev * u0;
    a1 += nvp[H + h]     * gsv + gev * u1;
    a2 += nvp[2 * H + h] * gsv + gev * u2;
  }

  ns[(size_t)i * H + h] += accs;
  const float* nvi = nvA + (size_t)i * F3H;
  nvB[(size_t)i * F3H + h]         = nvi[h] + a0;
  nvB[(size_t)i * F3H + H + h]     = nvi[H + h] + a1;
  nvB[(size_t)i * F3H + 2 * H + h] = nvi[2 * H + h] + a2;
}

// ---------------- gating epilogue ----------------
__global__ __launch_bounds__(H) void epilogue(
    float* __restrict__ ns, float* __restrict__ nv,
    const float* __restrict__ Uv, const float* __restrict__ Vv,
    const float* __restrict__ mo, int N) {
  int i = blockIdx.x;
  int h = threadIdx.x;
  float avv = mo[(size_t)i * F3H + h];
  float asv = mo[(size_t)i * F3H + H + h];
  float ass = mo[(size_t)i * F3H + 2 * H + h];
  float u0 = Uv[(size_t)(3 * i + 0) * H + h];
  float u1 = Uv[(size_t)(3 * i + 1) * H + h];
  float u2 = Uv[(size_t)(3 * i + 2) * H + h];
  float v0 = Vv[(size_t)(3 * i + 0) * H + h];
  float v1 = Vv[(size_t)(3 * i + 1) * H + h];
  float v2 = Vv[(size_t)(3 * i + 2) * H + h];
  float dot = u0 * v0 + u1 * v1 + u2 * v2;
  ns[(size_t)i * H + h] += asv * dot + ass;
  nv[(size_t)i * F3H + h]         += avv * u0;
  nv[(size_t)i * F3H + H + h]     += avv * u1;
  nv[(size_t)i * F3H + 2 * H + h] += avv * u2;
}

extern "C" void kernel_launch(void* const* d_in, const int* in_sizes, int n_in,
                              void* d_out, int out_size, void* d_ws, size_t ws_size,
                              hipStream_t stream) {
  const int*   z     = (const int*)d_in[0];
  const int*   edge  = (const int*)d_in[1];
  const float* ediff = (const float*)d_in[2];
  const float* edist = (const float*)d_in[3];
  const float* embed = (const float*)d_in[4];
  const float* mfw   = (const float*)d_in[5];
  const float* mfb   = (const float*)d_in[6];
  const float* mw1   = (const float*)d_in[7];
  const float* mb1   = (const float*)d_in[8];
  const float* mw2   = (const float*)d_in[9];
  const float* mb2   = (const float*)d_in[10];
  const float* uUw   = (const float*)d_in[11];
  const float* uUb   = (const float*)d_in[12];
  const float* uVw   = (const float*)d_in[13];
  const float* uVb   = (const float*)d_in[14];
  const float* uw1   = (const float*)d_in[15];
  const float* ub1   = (const float*)d_in[16];
  const float* uw2   = (const float*)d_in[17];
  const float* ub2   = (const float*)d_in[18];
  const float* rw1   = (const float*)d_in[19];
  const float* rb1   = (const float*)d_in[20];
  const float* rw2   = (const float*)d_in[21];
  const float* rb2   = (const float*)d_in[22];

  const int N  = in_sizes[0];   // 10000
  const int nE = in_sizes[3];   // 160000

  float* ws = (float*)d_ws;
  size_t off = 0;
  float* ns   = ws + off; off += (size_t)N * H;
  float* nvA  = ws + off; off += (size_t)N * F3H;
  float* nvB  = ws + off; off += (size_t)N * F3H;
  float* so   = ws + off; off += (size_t)N * F3H;   // also reused as mo
  float* Vv   = ws + off; off += (size_t)N * F3H;
  float* scr1 = ws + off; off += (size_t)N * H;     // h1 / m1 / r1
  int* cnt      = (int*)(ws + off); off += N;
  int* rowstart = (int*)(ws + off); off += N;
  int* cur      = (int*)(ws + off); off += N;
  int* elist    = (int*)(ws + off); off += nE;

  const int tilesN  = (N + 31) / 32;        // 313
  const int tiles3N = (3 * N + 31) / 32;    // 938

  hipMemsetAsync(cnt, 0, (size_t)N * sizeof(int), stream);
  csr_hist<<<(nE + 255) / 256, 256, 0, stream>>>(edge, cnt, nE);
  csr_scan<<<1, 256, 0, stream>>>(cnt, rowstart, cur, N);
  csr_fill<<<(nE + 255) / 256, 256, 0, stream>>>(edge, cur, elist, nE);

  node_init<<<N, H, 0, stream>>>(z, embed, ns, nvA, N);

  float* nv_cur = nvA;
  float* nv_nxt = nvB;
  for (int l = 0; l < NLAYER; l++) {
    // so = silu(ns@mw1+b1)@mw2+b2
    gemm_t<H, true><<<tilesN, 256, 0, stream>>>(
        ns, mw1 + (size_t)l * H * H, mb1 + (size_t)l * H, scr1, N, H, 1);
    gemm_t<H, false><<<tilesN * 3, 256, 0, stream>>>(
        scr1, mw2 + (size_t)l * H * F3H, mb2 + (size_t)l * F3H, so, N, F3H, 3);

    message2<<<N, H, 0, stream>>>(edge, rowstart, cnt, elist, edist, ediff,
                                  mfw + (size_t)l * E_RBF * F3H, mfb + (size_t)l * F3H,
                                  so, nv_cur, ns, nv_nxt, N);

    float* Uv = nv_cur;  // dead after message2 — reuse as Uv scratch
    gemm_uv<<<tiles3N, 256, 0, stream>>>(
        nv_nxt,
        uUw + (size_t)l * H * H, uUb + (size_t)l * H,
        uVw + (size_t)l * H * H, uVb + (size_t)l * H,
        Uv, Vv, 3 * N);

    gemm_mid<<<tilesN, 256, 0, stream>>>(
        Vv, ns, uw1 + (size_t)l * 2 * H * H, ub1 + (size_t)l * H, scr1, N);
    float* mo = so;      // so consumed by message2 — reuse as mo
    gemm_t<H, false><<<tilesN * 3, 256, 0, stream>>>(
        scr1, uw2 + (size_t)l * H * F3H, ub2 + (size_t)l * F3H, mo, N, F3H, 3);

    epilogue<<<N, H, 0, stream>>>(ns, nv_nxt, Uv, Vv, mo, N);

    float* t = nv_cur; nv_cur = nv_nxt; nv_nxt = t;
  }

  gemm_t<H, true><<<tilesN, 256, 0, stream>>>(ns, rw1, rb1, scr1, N, H, 1);
  gemm_t<H, false><<<tilesN, 256, 0, stream>>>(scr1, rw2, rb2, (float*)d_out, N, H, 1);
}

// Round 8
// 970.929 us; speedup vs baseline: 1.8360x; 1.1364x over previous
//
#include <hip/hip_runtime.h>
#include <hip/hip_bf16.h>

#define H 128
#define F3H 384
#define E_RBF 20
#define NLAYER 3

__device__ __forceinline__ float silu_f(float x) { return x / (1.0f + __expf(-x)); }

constexpr float PI_F = 3.14159265358979323846f;
constexpr float CUT = 5.0f;

// ---------------- CSR build ----------------
__global__ __launch_bounds__(256) void csr_hist(
    const int* __restrict__ edge, int* __restrict__ cnt, int nE) {
  int e = blockIdx.x * blockDim.x + threadIdx.x;
  if (e < nE) atomicAdd(&cnt[edge[2 * e]], 1);
}

__global__ __launch_bounds__(256) void csr_scan(
    const int* __restrict__ cnt, int* __restrict__ rowstart, int* __restrict__ cur, int N) {
  __shared__ int part[256];
  int t = threadIdx.x;
  int chunk = (N + 255) / 256;
  int lo = t * chunk; if (lo > N) lo = N;
  int hi = lo + chunk; if (hi > N) hi = N;
  int s = 0;
  for (int i = lo; i < hi; i++) s += cnt[i];
  part[t] = s;
  __syncthreads();
  if (t == 0) {
    int r = 0;
    for (int i = 0; i < 256; i++) { int v = part[i]; part[i] = r; r += v; }
  }
  __syncthreads();
  int r = part[t];
  for (int i = lo; i < hi; i++) { rowstart[i] = r; cur[i] = r; r += cnt[i]; }
}

__global__ __launch_bounds__(256) void csr_fill(
    const int* __restrict__ edge, int* __restrict__ cur, int* __restrict__ elist, int nE) {
  int e = blockIdx.x * blockDim.x + threadIdx.x;
  if (e < nE) {
    int d = edge[2 * e];
    int p = atomicAdd(&cur[d], 1);
    elist[p] = e;
  }
}

// ---------------- edge geometry pack (once; layer-invariant) ----------------
// geo[j][0..19] = rbf_k * fcut ; geo[j][20..22] = unit ; geo[j][23] = fcut
__global__ __launch_bounds__(256) void edge_pack(
    const int* __restrict__ elist, const int* __restrict__ edge,
    const float* __restrict__ edist, const float* __restrict__ ediff,
    int* __restrict__ srcs, float* __restrict__ geo, int nE) {
  int j = blockIdx.x * blockDim.x + threadIdx.x;
  if (j >= nE) return;
  int e = elist[j];
  srcs[j] = edge[2 * e + 1];
  float d = edist[e];
  float inv = 1.0f / d;
  float th = d * (PI_F / CUT);
  float s1 = sinf(th), c1 = cosf(th);
  float fc = (d < CUT) ? 0.5f * (c1 + 1.0f) : 0.0f;
  float* g = geo + (size_t)j * 24;
  float twoc = 2.0f * c1;
  float skp = 0.0f, sk = s1;
  #pragma unroll
  for (int k = 0; k < E_RBF; k++) {
    g[k] = sk * inv * fc;
    float nx = twoc * sk - skp;
    skp = sk; sk = nx;
  }
  g[20] = ediff[3 * (size_t)e] * inv;
  g[21] = ediff[3 * (size_t)e + 1] * inv;
  g[22] = ediff[3 * (size_t)e + 2] * inv;
  g[23] = fc;
}

// ---------------- node init ----------------
__global__ __launch_bounds__(H) void node_init(
    const int* __restrict__ z, const float* __restrict__ embed,
    float* __restrict__ ns, float* __restrict__ nv, int N) {
  int i = blockIdx.x;
  int h = threadIdx.x;
  ns[(size_t)i * H + h] = embed[(size_t)z[i] * H + h];
  #pragma unroll
  for (int d = 0; d < 3; d++) nv[(size_t)i * F3H + d * H + h] = 0.0f;
}

// ---------------- generic register-tiled GEMM ----------------
template<int K, bool ACT>
__global__ __launch_bounds__(256) void gemm_t(
    const float* __restrict__ A, const float* __restrict__ W,
    const float* __restrict__ bias, float* __restrict__ C,
    int M, int cols, int npanels) {
  __shared__ float s_a[32][K + 4];
  int bx = blockIdx.x;
  int panel = bx % npanels;
  int tile  = bx / npanels;
  int i0 = tile * 32;
  int colbase = panel * 128;
  int tid = threadIdx.x;
  for (int idx = tid; idx < 32 * K; idx += 256) {
    int r = idx / K, k = idx - r * K;
    int gr = i0 + r;
    s_a[r][k] = (gr < M) ? A[(size_t)gr * K + k] : 0.0f;
  }
  __syncthreads();
  int mq = tid >> 5, hq = tid & 31;
  int col = colbase + 4 * hq;
  const float* Wp = W + col;
  float acc[4][4] = {};
  for (int k0 = 0; k0 < K; k0 += 4) {
    float4 av[4], wv[4];
    #pragma unroll
    for (int i = 0; i < 4; i++) av[i] = *(const float4*)&s_a[4 * mq + i][k0];
    #pragma unroll
    for (int kk = 0; kk < 4; kk++) wv[kk] = *(const float4*)&Wp[(size_t)(k0 + kk) * cols];
    #pragma unroll
    for (int kk = 0; kk < 4; kk++) {
      #pragma unroll
      for (int i = 0; i < 4; i++) {
        float a = ((const float*)&av[i])[kk];
        acc[i][0] += a * wv[kk].x;
        acc[i][1] += a * wv[kk].y;
        acc[i][2] += a * wv[kk].z;
        acc[i][3] += a * wv[kk].w;
      }
    }
  }
  float4 bj = *(const float4*)&bias[col];
  #pragma unroll
  for (int i = 0; i < 4; i++) {
    int gr = i0 + 4 * mq + i;
    if (gr < M) {
      float4 o;
      o.x = acc[i][0] + bj.x; o.y = acc[i][1] + bj.y;
      o.z = acc[i][2] + bj.z; o.w = acc[i][3] + bj.w;
      if (ACT) { o.x = silu_f(o.x); o.y = silu_f(o.y); o.z = silu_f(o.z); o.w = silu_f(o.w); }
      *(float4*)&C[(size_t)gr * cols + col] = o;
    }
  }
}

// ---------------- dual GEMM: Uv and Vv ----------------
__global__ __launch_bounds__(256) void gemm_uv(
    const float* __restrict__ A,
    const float* __restrict__ Wu, const float* __restrict__ bu,
    const float* __restrict__ Wv, const float* __restrict__ bv,
    float* __restrict__ Cu, float* __restrict__ Cv, int M) {
  __shared__ float s_a[32][132];
  int i0 = blockIdx.x * 32;
  int tid = threadIdx.x;
  for (int idx = tid; idx < 32 * 128; idx += 256) {
    int r = idx >> 7, k = idx & 127;
    int gr = i0 + r;
    s_a[r][k] = (gr < M) ? A[(size_t)gr * H + k] : 0.0f;
  }
  __syncthreads();
  int mq = tid >> 5, hq = tid & 31;
  int col = 4 * hq;
  const float* Wup = Wu + col;
  const float* Wvp = Wv + col;
  float au[4][4] = {}, av_[4][4] = {};
  for (int k0 = 0; k0 < 128; k0 += 4) {
    float4 aa[4], wu4[4], wv4[4];
    #pragma unroll
    for (int i = 0; i < 4; i++) aa[i] = *(const float4*)&s_a[4 * mq + i][k0];
    #pragma unroll
    for (int kk = 0; kk < 4; kk++) {
      wu4[kk] = *(const float4*)&Wup[(size_t)(k0 + kk) * H];
      wv4[kk] = *(const float4*)&Wvp[(size_t)(k0 + kk) * H];
    }
    #pragma unroll
    for (int kk = 0; kk < 4; kk++) {
      #pragma unroll
      for (int i = 0; i < 4; i++) {
        float a = ((const float*)&aa[i])[kk];
        au[i][0] += a * wu4[kk].x; au[i][1] += a * wu4[kk].y;
        au[i][2] += a * wu4[kk].z; au[i][3] += a * wu4[kk].w;
        av_[i][0] += a * wv4[kk].x; av_[i][1] += a * wv4[kk].y;
        av_[i][2] += a * wv4[kk].z; av_[i][3] += a * wv4[kk].w;
      }
    }
  }
  float4 bu4 = *(const float4*)&bu[col];
  float4 bv4 = *(const float4*)&bv[col];
  #pragma unroll
  for (int i = 0; i < 4; i++) {
    int gr = i0 + 4 * mq + i;
    if (gr < M) {
      float4 ou, ov;
      ou.x = au[i][0] + bu4.x; ou.y = au[i][1] + bu4.y; ou.z = au[i][2] + bu4.z; ou.w = au[i][3] + bu4.w;
      ov.x = av_[i][0] + bv4.x; ov.y = av_[i][1] + bv4.y; ov.z = av_[i][2] + bv4.z; ov.w = av_[i][3] + bv4.w;
      *(float4*)&Cu[(size_t)gr * H + col] = ou;
      *(float4*)&Cv[(size_t)gr * H + col] = ov;
    }
  }
}

// ---------------- update-MLP layer1: A = [||Vv||, ns], K=256, silu ----------------
__global__ __launch_bounds__(256) void gemm_mid(
    const float* __restrict__ Vv, const float* __restrict__ ns,
    const float* __restrict__ W, const float* __restrict__ bias,
    float* __restrict__ C, int M) {
  __shared__ float s_a[32][260];
  int i0 = blockIdx.x * 32;
  int tid = threadIdx.x;
  for (int idx = tid; idx < 32 * 256; idx += 256) {
    int r = idx >> 8, k = idx & 255;
    int gr = i0 + r;
    float val = 0.0f;
    if (gr < M) {
      if (k < H) {
        float v0 = Vv[(size_t)(3 * gr + 0) * H + k];
        float v1 = Vv[(size_t)(3 * gr + 1) * H + k];
        float v2 = Vv[(size_t)(3 * gr + 2) * H + k];
        val = sqrtf(v0 * v0 + v1 * v1 + v2 * v2);
      } else {
        val = ns[(size_t)gr * H + (k - H)];
      }
    }
    s_a[r][k] = val;
  }
  __syncthreads();
  int mq = tid >> 5, hq = tid & 31;
  int col = 4 * hq;
  const float* Wp = W + col;
  float acc[4][4] = {};
  for (int k0 = 0; k0 < 256; k0 += 4) {
    float4 aa[4], wv[4];
    #pragma unroll
    for (int i = 0; i < 4; i++) aa[i] = *(const float4*)&s_a[4 * mq + i][k0];
    #pragma unroll
    for (int kk = 0; kk < 4; kk++) wv[kk] = *(const float4*)&Wp[(size_t)(k0 + kk) * H];
    #pragma unroll
    for (int kk = 0; kk < 4; kk++) {
      #pragma unroll
      for (int i = 0; i < 4; i++) {
        float a = ((const float*)&aa[i])[kk];
        acc[i][0] += a * wv[kk].x; acc[i][1] += a * wv[kk].y;
        acc[i][2] += a * wv[kk].z; acc[i][3] += a * wv[kk].w;
      }
    }
  }
  float4 bj = *(const float4*)&bias[col];
  #pragma unroll
  for (int i = 0; i < 4; i++) {
    int gr = i0 + 4 * mq + i;
    if (gr < M) {
      float4 o;
      o.x = silu_f(acc[i][0] + bj.x); o.y = silu_f(acc[i][1] + bj.y);
      o.z = silu_f(acc[i][2] + bj.z); o.w = silu_f(acc[i][3] + bj.w);
      *(float4*)&C[(size_t)gr * H + col] = o;
    }
  }
}

// ---------------- message v3: precomputed geo, register-resident Wf ----------------
__global__ __launch_bounds__(128, 4) void message3(
    const int* __restrict__ srcs, const int* __restrict__ rowstart,
    const int* __restrict__ cnt, const float* __restrict__ geo,
    const float* __restrict__ Wf, const float* __restrict__ bfb,
    const float* __restrict__ so, const float* __restrict__ nvA,
    float* __restrict__ ns, float* __restrict__ nvB, int N) {
  int i = blockIdx.x;
  int h = threadIdx.x;

  float wf0[E_RBF], wf1[E_RBF], wf2[E_RBF];
  #pragma unroll
  for (int k = 0; k < E_RBF; k++) {
    wf0[k] = Wf[k * F3H + h];
    wf1[k] = Wf[k * F3H + H + h];
    wf2[k] = Wf[k * F3H + 2 * H + h];
  }
  float bb0 = bfb[h], bb1 = bfb[H + h], bb2 = bfb[2 * H + h];

  float accs = 0.0f, a0 = 0.0f, a1 = 0.0f, a2 = 0.0f;
  int jlo = rowstart[i], jhi = jlo + cnt[i];
  for (int j = jlo; j < jhi; j++) {
    int src = srcs[j];
    const float* g = geo + (size_t)j * 24;
    float gg[24];
    #pragma unroll
    for (int q = 0; q < 6; q++) *(float4*)&gg[4 * q] = *(const float4*)&g[4 * q];

    float fc = gg[23];
    float f0 = bb0 * fc, f1 = bb1 * fc, f2 = bb2 * fc;
    #pragma unroll
    for (int k = 0; k < E_RBF; k++) {
      float rk = gg[k];            // rbf_k * fcut
      f0 += rk * wf0[k];
      f1 += rk * wf1[k];
      f2 += rk * wf2[k];
    }
    float u0 = gg[20], u1 = gg[21], u2 = gg[22];

    const float* sop = so + (size_t)src * F3H;
    float gsv = f0 * sop[h];
    float gev = f1 * sop[H + h];
    accs += f2 * sop[2 * H + h];

    const float* nvp = nvA + (size_t)src * F3H;
    a0 += nvp[h]         * gsv + gev * u0;
    a1 += nvp[H + h]     * gsv + gev * u1;
    a2 += nvp[2 * H + h] * gsv + gev * u2;
  }

  ns[(size_t)i * H + h] += accs;
  const float* nvi = nvA + (size_t)i * F3H;
  nvB[(size_t)i * F3H + h]         = nvi[h] + a0;
  nvB[(size_t)i * F3H + H + h]     = nvi[H + h] + a1;
  nvB[(size_t)i * F3H + 2 * H + h] = nvi[2 * H + h] + a2;
}

// ---------------- gating epilogue ----------------
__global__ __launch_bounds__(H) void epilogue(
    float* __restrict__ ns, float* __restrict__ nv,
    const float* __restrict__ Uv, const float* __restrict__ Vv,
    const float* __restrict__ mo, int N) {
  int i = blockIdx.x;
  int h = threadIdx.x;
  float avv = mo[(size_t)i * F3H + h];
  float asv = mo[(size_t)i * F3H + H + h];
  float ass = mo[(size_t)i * F3H + 2 * H + h];
  float u0 = Uv[(size_t)(3 * i + 0) * H + h];
  float u1 = Uv[(size_t)(3 * i + 1) * H + h];
  float u2 = Uv[(size_t)(3 * i + 2) * H + h];
  float v0 = Vv[(size_t)(3 * i + 0) * H + h];
  float v1 = Vv[(size_t)(3 * i + 1) * H + h];
  float v2 = Vv[(size_t)(3 * i + 2) * H + h];
  float dot = u0 * v0 + u1 * v1 + u2 * v2;
  ns[(size_t)i * H + h] += asv * dot + ass;
  nv[(size_t)i * F3H + h]         += avv * u0;
  nv[(size_t)i * F3H + H + h]     += avv * u1;
  nv[(size_t)i * F3H + 2 * H + h] += avv * u2;
}

extern "C" void kernel_launch(void* const* d_in, const int* in_sizes, int n_in,
                              void* d_out, int out_size, void* d_ws, size_t ws_size,
                              hipStream_t stream) {
  const int*   z     = (const int*)d_in[0];
  const int*   edge  = (const int*)d_in[1];
  const float* ediff = (const float*)d_in[2];
  const float* edist = (const float*)d_in[3];
  const float* embed = (const float*)d_in[4];
  const float* mfw   = (const float*)d_in[5];
  const float* mfb   = (const float*)d_in[6];
  const float* mw1   = (const float*)d_in[7];
  const float* mb1   = (const float*)d_in[8];
  const float* mw2   = (const float*)d_in[9];
  const float* mb2   = (const float*)d_in[10];
  const float* uUw   = (const float*)d_in[11];
  const float* uUb   = (const float*)d_in[12];
  const float* uVw   = (const float*)d_in[13];
  const float* uVb   = (const float*)d_in[14];
  const float* uw1   = (const float*)d_in[15];
  const float* ub1   = (const float*)d_in[16];
  const float* uw2   = (const float*)d_in[17];
  const float* ub2   = (const float*)d_in[18];
  const float* rw1   = (const float*)d_in[19];
  const float* rb1   = (const float*)d_in[20];
  const float* rw2   = (const float*)d_in[21];
  const float* rb2   = (const float*)d_in[22];

  const int N  = in_sizes[0];   // 10000
  const int nE = in_sizes[3];   // 160000

  float* ws = (float*)d_ws;
  size_t off = 0;
  float* ns   = ws + off; off += (size_t)N * H;
  float* nvA  = ws + off; off += (size_t)N * F3H;
  float* nvB  = ws + off; off += (size_t)N * F3H;
  float* so   = ws + off; off += (size_t)N * F3H;   // reused as mo
  float* Vv   = ws + off; off += (size_t)N * F3H;
  float* scr1 = ws + off; off += (size_t)N * H;
  float* geo  = ws + off; off += (size_t)nE * 24;
  int* srcs     = (int*)(ws + off); off += nE;
  int* cnt      = (int*)(ws + off); off += N;
  int* rowstart = (int*)(ws + off); off += N;
  int* cur      = (int*)(ws + off); off += N;
  int* elist    = (int*)(ws + off); off += nE;

  const int tilesN  = (N + 31) / 32;
  const int tiles3N = (3 * N + 31) / 32;

  hipMemsetAsync(cnt, 0, (size_t)N * sizeof(int), stream);
  csr_hist<<<(nE + 255) / 256, 256, 0, stream>>>(edge, cnt, nE);
  csr_scan<<<1, 256, 0, stream>>>(cnt, rowstart, cur, N);
  csr_fill<<<(nE + 255) / 256, 256, 0, stream>>>(edge, cur, elist, nE);
  edge_pack<<<(nE + 255) / 256, 256, 0, stream>>>(elist, edge, edist, ediff, srcs, geo, nE);

  node_init<<<N, H, 0, stream>>>(z, embed, ns, nvA, N);

  float* nv_cur = nvA;
  float* nv_nxt = nvB;
  for (int l = 0; l < NLAYER; l++) {
    gemm_t<H, true><<<tilesN, 256, 0, stream>>>(
        ns, mw1 + (size_t)l * H * H, mb1 + (size_t)l * H, scr1, N, H, 1);
    gemm_t<H, false><<<tilesN * 3, 256, 0, stream>>>(
        scr1, mw2 + (size_t)l * H * F3H, mb2 + (size_t)l * F3H, so, N, F3H, 3);

    message3<<<N, H, 0, stream>>>(srcs, rowstart, cnt, geo,
                                  mfw + (size_t)l * E_RBF * F3H, mfb + (size_t)l * F3H,
                                  so, nv_cur, ns, nv_nxt, N);

    float* Uv = nv_cur;  // dead after message3 — reuse as Uv scratch
    gemm_uv<<<tiles3N, 256, 0, stream>>>(
        nv_nxt,
        uUw + (size_t)l * H * H, uUb + (size_t)l * H,
        uVw + (size_t)l * H * H, uVb + (size_t)l * H,
        Uv, Vv, 3 * N);

    gemm_mid<<<tilesN, 256, 0, stream>>>(
        Vv, ns, uw1 + (size_t)l * 2 * H * H, ub1 + (size_t)l * H, scr1, N);
    float* mo = so;
    gemm_t<H, false><<<tilesN * 3, 256, 0, stream>>>(
        scr1, uw2 + (size_t)l * H * F3H, ub2 + (size_t)l * F3H, mo, N, F3H, 3);

    epilogue<<<N, H, 0, stream>>>(ns, nv_nxt, Uv, Vv, mo, N);

    float* t = nv_cur; nv_cur = nv_nxt; nv_nxt = t;
  }

  gemm_t<H, true><<<tilesN, 256, 0, stream>>>(ns, rw1, rb1, scr1, N, H, 1);
  gemm_t<H, false><<<tilesN, 256, 0, stream>>>(scr1, rw2, rb2, (float*)d_out, N, H, 1);
}